// Round 2
// baseline (834.634 us; speedup 1.0000x reference)
//
#include <hip/hip_runtime.h>
#include <cstdint>
#include <cstddef>

// Problem constants (from reference)
#define TOKENS 2048
#define IN_F   4096
#define OUT_F  11008
#define W_BIT  4
#define RANK   16
#define QWB    (OUT_F * IN_F / 8)   // 5,636,096 int32 "bytes" per bit-plane

typedef unsigned short ushort_t;
typedef __attribute__((ext_vector_type(8))) short   short8;   // 8 bf16 = 4 VGPRs (MFMA A/B frag)
typedef __attribute__((ext_vector_type(4))) float   floatx4;  // MFMA C/D frag

__device__ __forceinline__ ushort_t f2bf(float f) {
  union { float f; uint32_t u; } c; c.f = f;
  uint32_t r = c.u + 0x7FFFu + ((c.u >> 16) & 1u);  // RNE
  return (ushort_t)(r >> 16);
}

// async global->LDS, 16B per lane; lds pointer must be wave-uniform base (HW adds lane*16)
__device__ __forceinline__ void gl_lds16(const void* g, void* l) {
  __builtin_amdgcn_global_load_lds(
      (const __attribute__((address_space(1))) uint32_t*)g,
      (__attribute__((address_space(3))) uint32_t*)l, 16, 0, 0);
}

// ---------------- phase 0a: x fp32 -> bf16 ----------------
__global__ __launch_bounds__(256) void k_cvt_x(const float* __restrict__ x,
                                               ushort_t* __restrict__ xb) {
  int idx = blockIdx.x * 256 + threadIdx.x;
  float4 v = ((const float4*)x)[idx];
  ushort4 r;
  r.x = f2bf(v.x); r.y = f2bf(v.y); r.z = f2bf(v.z); r.w = f2bf(v.w);
  ((ushort4*)xb)[idx] = r;
}

// ---------------- phase 0b: u -> bf16 (same layout), vt -> bf16 transposed ----------------
#define N_U  (W_BIT * OUT_F * RANK)   // 704512
#define N_VT (W_BIT * RANK * IN_F)    // 262144
__global__ __launch_bounds__(256) void k_prep_uv(const float* __restrict__ u,
                                                 const float* __restrict__ vt,
                                                 ushort_t* __restrict__ ub,
                                                 ushort_t* __restrict__ vtT) {
  int idx = blockIdx.x * 256 + threadIdx.x;
  if (idx < N_U) {
    ub[idx] = f2bf(u[idx]);
  } else {
    int e = idx - N_U;                 // [0, N_VT)
    int b = e >> 16;                   // RANK*IN_F = 65536
    int r = e & 65535;
    int k = r >> 12;                   // IN_F = 4096
    int i = r & 4095;
    vtT[((size_t)b * IN_F + i) * RANK + k] = f2bf(vt[e]);
  }
}

// ---------------- phase 1: build w (bf16): MFMA product + LDS-staged sign apply ----
// Sign-int reads are now ds_read_b128: qs int columns are PERMUTED within each 8-int
// group (p' = ((p&1)<<2)|(p>>1)) so a lane's 4 ni-ints (orig cols qcb, qcb+2, qcb+4,
// qcb+6) sit contiguously. 256 scalar LDS reads/thread -> 64 vector reads/thread.
__global__ __launch_bounds__(256) void k_build_w(const int* __restrict__ qw,
                                                 const ushort_t* __restrict__ ub,
                                                 const ushort_t* __restrict__ vtT,
                                                 ushort_t* __restrict__ w) {
  __shared__ int qs[W_BIT * 128 * 20];  // 40 KB (row stride 20 ints = 80B, 16B-aligned)
  const int tid = threadIdx.x;
  const int ob = blockIdx.x / (IN_F / 128);
  const int ib = blockIdx.x % (IN_F / 128);
  const int o0 = ob * 128, i0 = ib * 128;
  const int lane = tid & 63, wv = tid >> 6;
  const int wm = (wv >> 1) * 64, wn = (wv & 1) * 64;
  const int l16 = lane & 15, q = lane >> 4;
  const bool qlo = (q < 2);
  const int koff = (q & 1) * 8;        // valid k-halves for q=0,1; q>=2 zeroed
  const short8 zf = (short8)0;

  // stage qw tile: 4 planes x 128 rows x 16 ints; 2048 int4 chunks, 8/thread, coalesced.
  // Scatter each int4 into the permuted column positions:
  //   orig within-8 pos p -> p' = ((p&1)<<2)|(p>>1); for chunk part, j=0..3:
  //   p' = (part&1)*2 + {0,4,1,5}[j]
  #pragma unroll
  for (int n = 0; n < 8; ++n) {
    int c = n * 256 + tid;             // [0, 2048)
    int b = c >> 9, rem = c & 511;
    int row = rem >> 2, part = rem & 3;
    int4 v = *(const int4*)(qw + (size_t)b * QWB +
                            (size_t)(o0 + row) * (IN_F / 8) + (i0 >> 3) + part * 4);
    int* qrow = &qs[(b * 128 + row) * 20 + (part >> 1) * 8 + (part & 1) * 2];
    qrow[0] = v.x; qrow[4] = v.y; qrow[1] = v.z; qrow[5] = v.w;
  }

  floatx4 acc[16];
  #pragma unroll
  for (int i = 0; i < 16; ++i) acc[i] = (floatx4){0.f, 0.f, 0.f, 0.f};

  // lane's 4 ni-ints now live at permuted positions qcol..qcol+3 (element k <-> ni=k)
  const int qc_base = (wn >> 3) + (l16 >> 3);              // in {0,1,8,9}
  const int qcol = (qc_base & 8) | ((qc_base & 1) << 2);   // in {0,4,8,12}
  const int bit = l16 & 7;

  __syncthreads();

  #pragma unroll
  for (int b = 0; b < W_BIT; ++b) {
    short8 af[4], bfr[4];
    #pragma unroll
    for (int mi = 0; mi < 4; ++mi) {
      short8 v = *(const short8*)&ub[((size_t)b * OUT_F + o0 + wm + mi * 16 + l16) * RANK + koff];
      af[mi] = qlo ? v : zf;
    }
    #pragma unroll
    for (int ni = 0; ni < 4; ++ni) {
      short8 v = *(const short8*)&vtT[((size_t)b * IN_F + i0 + wn + ni * 16 + l16) * RANK + koff];
      bfr[ni] = qlo ? v : zf;
    }

    #pragma unroll
    for (int mi = 0; mi < 4; ++mi) {
      floatx4 p[4];
      #pragma unroll
      for (int ni = 0; ni < 4; ++ni)
        p[ni] = __builtin_amdgcn_mfma_f32_16x16x32_bf16(
            af[mi], bfr[ni], (floatx4){0.f, 0.f, 0.f, 0.f}, 0, 0, 0);
      // C layout: col = l16, row = q*4 + v4  [verified m89/m91]
      #pragma unroll
      for (int v4 = 0; v4 < 4; ++v4) {
        const int o_loc = wm + mi * 16 + q * 4 + v4;
        const int4 qv4 = *(const int4*)&qs[(b * 128 + o_loc) * 20 + qcol];
        #pragma unroll
        for (int ni = 0; ni < 4; ++ni) {
          int qv = (ni == 0) ? qv4.x : (ni == 1) ? qv4.y : (ni == 2) ? qv4.z : qv4.w;
          float pv = p[ni][v4];
          acc[mi * 4 + ni][v4] += ((qv >> bit) & 1) ? pv : -pv;
        }
      }
    }
  }

  #pragma unroll
  for (int mi = 0; mi < 4; ++mi) {
    #pragma unroll
    for (int v4 = 0; v4 < 4; ++v4) {
      const int o = o0 + wm + mi * 16 + q * 4 + v4;
      #pragma unroll
      for (int ni = 0; ni < 4; ++ni)
        w[(size_t)o * IN_F + i0 + wn + ni * 16 + l16] = f2bf(acc[mi * 4 + ni][v4]);
    }
  }
}

// ---------------- phase 2: y = x @ w^T  (bf16 MFMA gemm_bt, 3-slot ring) ----------------
// M=2048, N=11008, K=4096. BM=128, BN=256, BK=32. 512 threads = 8 waves (2Mx4N),
// wave tile 64x64 = 4x4 frags of 16x16x32.
//
// Round-1 ring scaled to 3 slots (72 KB LDS) so TWO blocks co-reside per CU
// (4 waves/SIMD TLP; round-1's 96 KB ring allowed only 1 block = 2 waves/SIMD,
// and all-lockstep barriers left ~70% of cycles as unhidden latency).
//  - 3-slot LDS ring, prefetch depth 2, counted vmcnt(3) (never 0 mid-loop):
//    per tile: barrier -> STAGE(t+2) into slot of (t-1) -> vmcnt(3) [t+1 resident]
//    -> barrier -> LDFRAGS(t+1) into alternate regs -> 16 MFMA on tile t regs.
//    Slot-free proof: tile t-1's frag reads completed before its MFMAs (reg dep),
//    which completed before the top barrier of tile t.
//  - T2 bank swizzle unchanged (round-1 measured 0 conflicts): chunk^=((row>>1)&3),
//    inverse swizzle folded into the per-lane GLOBAL source address.
//  - T1 XCD swizzle unchanged (688 = 8*86 bijective).
#define NT (IN_F / 32)   // 128 K-tiles
#define SLOT_BYTES 24576  // A 8KB + B 16KB
__global__ __launch_bounds__(512, 4) void k_gemm_bt(const ushort_t* __restrict__ A,  // [2048][4096]
                                                    const ushort_t* __restrict__ B,  // [11008][4096]
                                                    float* __restrict__ C) {         // [2048][11008]
  __shared__ __attribute__((aligned(16))) char lds[3 * SLOT_BYTES];  // 72 KB
  const int tid = threadIdx.x;
  const int wg = (blockIdx.x & 7) * 86 + (blockIdx.x >> 3);  // bijective XCD swizzle
  const int bm = wg & 15;    // 16 M-tiles of 128
  const int bn = wg >> 4;    // 43 N-tiles of 256
  const int lane = tid & 63, wv = tid >> 6;
  const int wm = wv >> 2, wn = wv & 3;      // wave grid 2(M) x 4(N), wave tile 64x64
  const int l16 = lane & 15, q = lane >> 4;
  const int sQ = q ^ ((l16 >> 1) & 3);      // read-side swizzled 16B-chunk slot (thread const)

  const size_t ar = (size_t)bm * 128, br = (size_t)bn * 256;
  // staging: A-tile 128x32 = 512 chunks (1/thread); B-tile 256x32 = 1024 (2/thread)
  // chunk c: row = c>>2, slot16 = c&3, source k-chunk = slot ^ ((row>>1)&3)
  const int qsrc = (tid & 3) ^ ((tid >> 3) & 3);
  const ushort_t* Ae  = A + (ar + (tid >> 2)) * IN_F + qsrc * 8;
  const ushort_t* B0e = B + (br + (tid >> 2)) * IN_F + qsrc * 8;
  const ushort_t* B1e = B + (br + 128 + (tid >> 2)) * IN_F + qsrc * 8;
  const int ldsoff = (tid & 448) * 16;      // wave-uniform dest base (HW adds lane*16)
  const int aFrag = (wm * 64 + l16) * 64 + sQ * 16;   // byte off within A region (+mi*1024)
  const int bFrag = (wn * 64 + l16) * 64 + sQ * 16;   // byte off within B region (+ni*1024)

  floatx4 acc[4][4];
  #pragma unroll
  for (int mi = 0; mi < 4; ++mi)
    #pragma unroll
    for (int ni = 0; ni < 4; ++ni) acc[mi][ni] = (floatx4){0.f, 0.f, 0.f, 0.f};

  short8 a0[4], b0[4], a1[4], b1[4];
  int sC = 0, sA = SLOT_BYTES, sB = 2 * SLOT_BYTES;  // slots of tiles t, t+1, t+2

#define STAGE(tt, sb) do {                                                   \
    const size_t _k0 = (size_t)(tt) * 32;                                    \
    char* _d = lds + (sb) + ldsoff;                                          \
    gl_lds16(Ae + _k0,  _d);                                                 \
    gl_lds16(B0e + _k0, _d + 8192);                                          \
    gl_lds16(B1e + _k0, _d + 16384);                                         \
  } while (0)

#define LDFRAGS(AF, BF, sa) do {                                             \
    const char* _ab = lds + (sa);                                            \
    const char* _bb = _ab + 8192;                                            \
    _Pragma("unroll") for (int mi = 0; mi < 4; ++mi)                         \
      AF[mi] = *(const short8*)(_ab + aFrag + mi * 1024);                    \
    _Pragma("unroll") for (int ni = 0; ni < 4; ++ni)                         \
      BF[ni] = *(const short8*)(_bb + bFrag + ni * 1024);                    \
  } while (0)

#define BODY(u, AI, BI, AM, BMr) do {                                        \
    asm volatile("" ::: "memory");                                           \
    __builtin_amdgcn_s_barrier();        /* closes frag-reads of tile u-1 */ \
    asm volatile("" ::: "memory");                                           \
    if ((u) + 2 < NT) {                                                      \
      STAGE((u) + 2, sB);                /* into slot tile u-1 vacated */    \
      asm volatile("s_waitcnt vmcnt(3)" ::: "memory");  /* u+1 resident */   \
    } else {                                                                 \
      asm volatile("s_waitcnt vmcnt(0)" ::: "memory");                       \
    }                                                                        \
    __builtin_amdgcn_s_barrier();        /* publish tile u+1 residency */    \
    asm volatile("" ::: "memory");                                           \
    LDFRAGS(AI, BI, sA);                 /* prefetch frags of tile u+1 */    \
    __builtin_amdgcn_s_setprio(1);                                           \
    _Pragma("unroll") for (int mi = 0; mi < 4; ++mi)                         \
      _Pragma("unroll") for (int ni = 0; ni < 4; ++ni)                       \
        acc[mi][ni] = __builtin_amdgcn_mfma_f32_16x16x32_bf16(               \
            AM[mi], BMr[ni], acc[mi][ni], 0, 0, 0);                          \
    __builtin_amdgcn_s_setprio(0);                                           \
  } while (0)

#define ROTATE() do { int _t = sC; sC = sA; sA = sB; sB = _t; } while (0)

  // prologue: stage tiles 0,1 (6 loads out), wait tile 0 (allow 3), read its frags
  STAGE(0, sC); STAGE(1, sA);
  asm volatile("s_waitcnt vmcnt(3)" ::: "memory");
  __builtin_amdgcn_s_barrier();
  asm volatile("" ::: "memory");
  LDFRAGS(a0, b0, sC);

  for (int t = 0; t < NT; t += 2) {
    BODY(t,     a1, b1, a0, b0);
    ROTATE();
    BODY(t + 1, a0, b0, a1, b1);
    ROTATE();
  }

#undef STAGE
#undef LDFRAGS
#undef BODY
#undef ROTATE

  // C/D layout: col = lane&15, row = (lane>>4)*4 + reg  [verified m89/m91]
  #pragma unroll
  for (int mi = 0; mi < 4; ++mi) {
    #pragma unroll
    for (int ni = 0; ni < 4; ++ni) {
      #pragma unroll
      for (int v = 0; v < 4; ++v) {
        int r = bm * 128 + wm * 64 + mi * 16 + q * 4 + v;
        int c = bn * 256 + wn * 64 + ni * 16 + l16;
        C[(size_t)r * OUT_F + c] = acc[mi][ni][v];
      }
    }
  }
}

extern "C" void kernel_launch(void* const* d_in, const int* in_sizes, int n_in,
                              void* d_out, int out_size, void* d_ws, size_t ws_size,
                              hipStream_t stream) {
  (void)in_sizes; (void)n_in; (void)out_size; (void)ws_size;
  const float* x  = (const float*)d_in[0];
  const int*   qw = (const int*)d_in[1];
  const float* u  = (const float*)d_in[2];
  const float* vt = (const float*)d_in[3];
  float* out = (float*)d_out;

  // workspace layout (bytes):
  //   xb  @ 0         : 2048*4096*2   = 16,777,216
  //   wb  @ 16.0 MB   : 11008*4096*2  = 90,177,536
  //   ub  @ 102.0 MB  : 4*11008*16*2  = 1,409,024
  //   vtT @ 103.3 MB  : 4*4096*16*2   = 524,288     (total ~103.8 MiB)
  char* wsp = (char*)d_ws;
  ushort_t* xb  = (ushort_t*)wsp;
  ushort_t* wb  = (ushort_t*)(wsp + (size_t)TOKENS * IN_F * 2);
  ushort_t* ubf = (ushort_t*)(wsp + (size_t)TOKENS * IN_F * 2 + (size_t)OUT_F * IN_F * 2);
  ushort_t* vtT = (ushort_t*)(wsp + (size_t)TOKENS * IN_F * 2 + (size_t)OUT_F * IN_F * 2 +
                              (size_t)N_U * 2);

  k_cvt_x<<<TOKENS * IN_F / 1024, 256, 0, stream>>>(x, xb);
  k_prep_uv<<<(N_U + N_VT) / 256, 256, 0, stream>>>(u, vt, ubf, vtT);
  k_build_w<<<(OUT_F / 128) * (IN_F / 128), 256, 0, stream>>>(qw, ubf, vtT, wb);
  k_gemm_bt<<<16 * (OUT_F / 256), 512, 0, stream>>>(xb, wb, out);
}

// Round 3
// 461.120 us; speedup vs baseline: 1.8100x; 1.8100x over previous
//
#include <hip/hip_runtime.h>
#include <cstdint>
#include <cstddef>

// Problem constants (from reference)
#define TOKENS 2048
#define IN_F   4096
#define OUT_F  11008
#define W_BIT  4
#define RANK   16
#define QWB    (OUT_F * IN_F / 8)   // 5,636,096 int32 "bytes" per bit-plane

typedef unsigned short ushort_t;
typedef __attribute__((ext_vector_type(8))) short   short8;   // 8 bf16 = 4 VGPRs (MFMA A/B frag)
typedef __attribute__((ext_vector_type(4))) float   floatx4;  // MFMA C/D frag

__device__ __forceinline__ ushort_t f2bf(float f) {
  union { float f; uint32_t u; } c; c.f = f;
  uint32_t r = c.u + 0x7FFFu + ((c.u >> 16) & 1u);  // RNE
  return (ushort_t)(r >> 16);
}

// async global->LDS, 16B per lane; lds pointer must be wave-uniform base (HW adds lane*16)
__device__ __forceinline__ void gl_lds16(const void* g, void* l) {
  __builtin_amdgcn_global_load_lds(
      (const __attribute__((address_space(1))) uint32_t*)g,
      (__attribute__((address_space(3))) uint32_t*)l, 16, 0, 0);
}

// ---------------- phase 0a: x fp32 -> bf16 ----------------
__global__ __launch_bounds__(256) void k_cvt_x(const float* __restrict__ x,
                                               ushort_t* __restrict__ xb) {
  int idx = blockIdx.x * 256 + threadIdx.x;
  float4 v = ((const float4*)x)[idx];
  ushort4 r;
  r.x = f2bf(v.x); r.y = f2bf(v.y); r.z = f2bf(v.z); r.w = f2bf(v.w);
  ((ushort4*)xb)[idx] = r;
}

// ---------------- phase 0b: u -> bf16 (same layout), vt -> bf16 transposed ----------------
#define N_U  (W_BIT * OUT_F * RANK)   // 704512
#define N_VT (W_BIT * RANK * IN_F)    // 262144
__global__ __launch_bounds__(256) void k_prep_uv(const float* __restrict__ u,
                                                 const float* __restrict__ vt,
                                                 ushort_t* __restrict__ ub,
                                                 ushort_t* __restrict__ vtT) {
  int idx = blockIdx.x * 256 + threadIdx.x;
  if (idx < N_U) {
    ub[idx] = f2bf(u[idx]);
  } else {
    int e = idx - N_U;                 // [0, N_VT)
    int b = e >> 16;                   // RANK*IN_F = 65536
    int r = e & 65535;
    int k = r >> 12;                   // IN_F = 4096
    int i = r & 4095;
    vtT[((size_t)b * IN_F + i) * RANK + k] = f2bf(vt[e]);
  }
}

// ---------------- phase 1: build w (bf16): MFMA product + LDS-staged sign apply ----
// qs int columns PERMUTED within each 8-int group (p' = ((p&1)<<2)|(p>>1)) so a lane's
// 4 ni-ints are contiguous -> ds_read_b128 sign reads (64/thread instead of 256 scalar).
// NEW: epilogue stages the 128x128 bf16 tile through LDS (reusing qs) and writes w as
// fully-coalesced 256B rows (prev: 32B scattered segments; suspected write amplification).
__global__ __launch_bounds__(256) void k_build_w(const int* __restrict__ qw,
                                                 const ushort_t* __restrict__ ub,
                                                 const ushort_t* __restrict__ vtT,
                                                 ushort_t* __restrict__ w) {
  __shared__ int qs[W_BIT * 128 * 20];  // 40 KB (row stride 20 ints = 80B, 16B-aligned)
  const int tid = threadIdx.x;
  const int ob = blockIdx.x / (IN_F / 128);
  const int ib = blockIdx.x % (IN_F / 128);
  const int o0 = ob * 128, i0 = ib * 128;
  const int lane = tid & 63, wv = tid >> 6;
  const int wm = (wv >> 1) * 64, wn = (wv & 1) * 64;
  const int l16 = lane & 15, q = lane >> 4;
  const bool qlo = (q < 2);
  const int koff = (q & 1) * 8;        // valid k-halves for q=0,1; q>=2 zeroed
  const short8 zf = (short8)0;

  // stage qw tile: 4 planes x 128 rows x 16 ints; 2048 int4 chunks, 8/thread, coalesced.
  #pragma unroll
  for (int n = 0; n < 8; ++n) {
    int c = n * 256 + tid;             // [0, 2048)
    int b = c >> 9, rem = c & 511;
    int row = rem >> 2, part = rem & 3;
    int4 v = *(const int4*)(qw + (size_t)b * QWB +
                            (size_t)(o0 + row) * (IN_F / 8) + (i0 >> 3) + part * 4);
    int* qrow = &qs[(b * 128 + row) * 20 + (part >> 1) * 8 + (part & 1) * 2];
    qrow[0] = v.x; qrow[4] = v.y; qrow[1] = v.z; qrow[5] = v.w;
  }

  floatx4 acc[16];
  #pragma unroll
  for (int i = 0; i < 16; ++i) acc[i] = (floatx4){0.f, 0.f, 0.f, 0.f};

  // lane's 4 ni-ints live at permuted positions qcol..qcol+3 (element k <-> ni=k)
  const int qc_base = (wn >> 3) + (l16 >> 3);              // in {0,1,8,9}
  const int qcol = (qc_base & 8) | ((qc_base & 1) << 2);   // in {0,4,8,12}
  const int bit = l16 & 7;

  __syncthreads();

  #pragma unroll
  for (int b = 0; b < W_BIT; ++b) {
    short8 af[4], bfr[4];
    #pragma unroll
    for (int mi = 0; mi < 4; ++mi) {
      short8 v = *(const short8*)&ub[((size_t)b * OUT_F + o0 + wm + mi * 16 + l16) * RANK + koff];
      af[mi] = qlo ? v : zf;
    }
    #pragma unroll
    for (int ni = 0; ni < 4; ++ni) {
      short8 v = *(const short8*)&vtT[((size_t)b * IN_F + i0 + wn + ni * 16 + l16) * RANK + koff];
      bfr[ni] = qlo ? v : zf;
    }

    #pragma unroll
    for (int mi = 0; mi < 4; ++mi) {
      floatx4 p[4];
      #pragma unroll
      for (int ni = 0; ni < 4; ++ni)
        p[ni] = __builtin_amdgcn_mfma_f32_16x16x32_bf16(
            af[mi], bfr[ni], (floatx4){0.f, 0.f, 0.f, 0.f}, 0, 0, 0);
      // C layout: col = l16, row = q*4 + v4  [verified m89/m91]
      #pragma unroll
      for (int v4 = 0; v4 < 4; ++v4) {
        const int o_loc = wm + mi * 16 + q * 4 + v4;
        const int4 qv4 = *(const int4*)&qs[(b * 128 + o_loc) * 20 + qcol];
        #pragma unroll
        for (int ni = 0; ni < 4; ++ni) {
          int qv = (ni == 0) ? qv4.x : (ni == 1) ? qv4.y : (ni == 2) ? qv4.z : qv4.w;
          float pv = p[ni][v4];
          acc[mi * 4 + ni][v4] += ((qv >> bit) & 1) ? pv : -pv;
        }
      }
    }
  }

  // ---- coalesced epilogue: stage tile in LDS (reuse qs), stream 256B rows ----
  __syncthreads();                       // all qs sign-reads complete in ALL waves
  ushort_t* ws = (ushort_t*)qs;          // [128][144] ushort = 36,864 B <= 40 KB
  #pragma unroll
  for (int mi = 0; mi < 4; ++mi)
    #pragma unroll
    for (int v4 = 0; v4 < 4; ++v4) {
      const int o_loc = wm + mi * 16 + q * 4 + v4;
      #pragma unroll
      for (int ni = 0; ni < 4; ++ni)
        ws[o_loc * 144 + wn + ni * 16 + l16] = f2bf(acc[mi * 4 + ni][v4]);
    }
  __syncthreads();
  // 2048 b128 chunks: row = c>>4, ch = c&15; 16 consecutive threads = one 256B row
  #pragma unroll
  for (int n = 0; n < 8; ++n) {
    int c = n * 256 + tid;
    int row = c >> 4, ch = c & 15;
    short8 v = *(const short8*)&ws[row * 144 + ch * 8];
    *(short8*)&w[(size_t)(o0 + row) * IN_F + i0 + ch * 8] = v;
  }
}

// ---------------- phase 2: y = x @ w^T  (bf16 MFMA, per-phase interleave T3+T4) ----------
// M=2048, N=11008, K=4096. BM=128, BN=256, K-step 32. 512 threads = 8 waves (2Mx4N),
// wave tile 64x64 = 4x4 frags of 16x16x32; 16 MFMA per wave per step.
//
// 6-sub-slot LDS ring (6 x 24KB = 144KB, 1 block/CU), stage distance 4 steps,
// ONE barrier per step, steady vmcnt(9) (waits only the 4-step-old loads; ~3 phases
// of cover >> 900cyc HBM latency; never drains mid-loop).
// Per step u:  vmcnt -> barrier(publish step u) -> ds_read frags(u) -> issue STAGE(u+4)
//              -> setprio(1) 16 MFMA(frags u) setprio(0)
// Race proof: slot S(u+4)=S(u-2); its last readers (step u-2 ds_reads) completed
// before their MFMAs (reg dep), which precede barriers u-1,u; staging issues after
// barrier u. Residency: per-wave vmcnt then barrier orders ALL waves' loads before
// any read. Epilogue peels last 4 steps with exact waits 9/6/3/0.
// Swizzle + stage/frag addressing identical to the round-1-verified maps
// (0 bank conflicts measured): chunk ^= ((row>>1)&3), inverse on global source.
// Registers: acc 64 + two frag sets 64 + addr ~ 170 -> no spill, NO min-wave bound
// (round-2 lesson: a 128-reg cap caused 800MB scratch traffic).
#define NSTEP (IN_F / 32)   // 128
#define SLOT  24576         // A 8KB + B 16KB
#define NSLOT 6
__global__ __launch_bounds__(512) void k_gemm_bt(const ushort_t* __restrict__ A,  // [2048][4096]
                                                 const ushort_t* __restrict__ B,  // [11008][4096]
                                                 float* __restrict__ C) {         // [2048][11008]
  __shared__ __attribute__((aligned(16))) char lds[NSLOT * SLOT];  // 144 KB
  const int tid = threadIdx.x;
  const int wg = (blockIdx.x & 7) * 86 + (blockIdx.x >> 3);  // bijective XCD swizzle (688=8*86)
  const int bm = wg & 15;    // 16 M-tiles of 128
  const int bn = wg >> 4;    // 43 N-tiles of 256
  const int lane = tid & 63, wv = tid >> 6;
  const int wm = wv >> 2, wn = wv & 3;      // wave grid 2(M) x 4(N), wave tile 64x64
  const int l16 = lane & 15, q = lane >> 4;
  const int sQ = q ^ ((l16 >> 1) & 3);      // read-side swizzled 16B-chunk slot (thread const)

  const size_t ar = (size_t)bm * 128, br = (size_t)bn * 256;
  // staging: A-tile 128x32 = 512 chunks (1/thread); B-tile 256x32 = 1024 (2/thread)
  // chunk c: row = c>>2, dest 16B-slot = c&3, source k-chunk = slot ^ ((row>>1)&3)
  const int qsrc = (tid & 3) ^ ((tid >> 3) & 3);
  const ushort_t* Ae  = A + (ar + (tid >> 2)) * IN_F + qsrc * 8;
  const ushort_t* B0e = B + (br + (tid >> 2)) * IN_F + qsrc * 8;
  const ushort_t* B1e = B + (br + 128 + (tid >> 2)) * IN_F + qsrc * 8;
  const int ldsoff = (tid & 448) * 16;      // wave-uniform dest base (HW adds lane*16)
  const int aFrag = (wm * 64 + l16) * 64 + sQ * 16;   // byte off within A region (+mi*1024)
  const int bFrag = (wn * 64 + l16) * 64 + sQ * 16;   // byte off within B region (+ni*1024)

  floatx4 acc[4][4];
  #pragma unroll
  for (int mi = 0; mi < 4; ++mi)
    #pragma unroll
    for (int ni = 0; ni < 4; ++ni) acc[mi][ni] = (floatx4){0.f, 0.f, 0.f, 0.f};

  short8 fa0[4], fb0[4], fa1[4], fb1[4];
  int sRead = 0, sWrite = 4 * SLOT;         // uniform -> SALU

#define PHASE(u_, FA, FB, VM, DO_STAGE) do {                                 \
    asm volatile(VM ::: "memory");       /* my loads for step u_ done */     \
    asm volatile("" ::: "memory");                                           \
    __builtin_amdgcn_s_barrier();        /* all waves' loads published */    \
    asm volatile("" ::: "memory");                                           \
    {                                                                        \
      const char* _ab = lds + sRead;                                         \
      const char* _bb = _ab + 8192;                                          \
      _Pragma("unroll") for (int mi = 0; mi < 4; ++mi)                       \
        FA[mi] = *(const short8*)(_ab + aFrag + mi * 1024);                   \
      _Pragma("unroll") for (int ni = 0; ni < 4; ++ni)                       \
        FB[ni] = *(const short8*)(_bb + bFrag + ni * 1024);                   \
    }                                                                        \
    if (DO_STAGE) {                                                          \
      const size_t _k0 = (size_t)((u_) + 4) * 32;                            \
      char* _d = lds + sWrite + ldsoff;                                      \
      gl_lds16(Ae + _k0,  _d);                                               \
      gl_lds16(B0e + _k0, _d + 8192);                                        \
      gl_lds16(B1e + _k0, _d + 16384);                                       \
    }                                                                        \
    __builtin_amdgcn_s_setprio(1);                                           \
    _Pragma("unroll") for (int mi = 0; mi < 4; ++mi)                         \
      _Pragma("unroll") for (int ni = 0; ni < 4; ++ni)                       \
        acc[mi][ni] = __builtin_amdgcn_mfma_f32_16x16x32_bf16(               \
            FA[mi], FB[ni], acc[mi][ni], 0, 0, 0);                           \
    __builtin_amdgcn_s_setprio(0);                                           \
    sRead += SLOT;  if (sRead  == NSLOT * SLOT) sRead  = 0;                  \
    sWrite += SLOT; if (sWrite == NSLOT * SLOT) sWrite = 0;                  \
  } while (0)

  // prologue: stage steps 0..3 into slots 0..3 (12 loads in flight)
  #pragma unroll
  for (int p = 0; p < 4; ++p) {
    char* _d = lds + p * SLOT + ldsoff;
    const size_t _k0 = (size_t)p * 32;
    gl_lds16(Ae + _k0,  _d);
    gl_lds16(B0e + _k0, _d + 8192);
    gl_lds16(B1e + _k0, _d + 16384);
  }

  // steady state: wait vmcnt(9) = only the 4-step-old 3 loads; stage step u+4
  for (int u = 0; u < NSTEP - 4; u += 2) {
    PHASE(u,     fa0, fb0, "s_waitcnt vmcnt(9)", true);
    PHASE(u + 1, fa1, fb1, "s_waitcnt vmcnt(9)", true);
  }
  // epilogue: no more staging; outstanding counts shrink 9/6/3/0
  PHASE(NSTEP - 4, fa0, fb0, "s_waitcnt vmcnt(9)", false);
  PHASE(NSTEP - 3, fa1, fb1, "s_waitcnt vmcnt(6)", false);
  PHASE(NSTEP - 2, fa0, fb0, "s_waitcnt vmcnt(3)", false);
  PHASE(NSTEP - 1, fa1, fb1, "s_waitcnt vmcnt(0)", false);

#undef PHASE

  // C/D layout: col = lane&15, row = (lane>>4)*4 + reg  [verified m89/m91]
  #pragma unroll
  for (int mi = 0; mi < 4; ++mi) {
    #pragma unroll
    for (int ni = 0; ni < 4; ++ni) {
      #pragma unroll
      for (int v = 0; v < 4; ++v) {
        int r = bm * 128 + wm * 64 + mi * 16 + q * 4 + v;
        int c = bn * 256 + wn * 64 + ni * 16 + l16;
        C[(size_t)r * OUT_F + c] = acc[mi][ni][v];
      }
    }
  }
}

extern "C" void kernel_launch(void* const* d_in, const int* in_sizes, int n_in,
                              void* d_out, int out_size, void* d_ws, size_t ws_size,
                              hipStream_t stream) {
  (void)in_sizes; (void)n_in; (void)out_size; (void)ws_size;
  const float* x  = (const float*)d_in[0];
  const int*   qw = (const int*)d_in[1];
  const float* u  = (const float*)d_in[2];
  const float* vt = (const float*)d_in[3];
  float* out = (float*)d_out;

  // workspace layout (bytes):
  //   xb  @ 0         : 2048*4096*2   = 16,777,216
  //   wb  @ 16.0 MB   : 11008*4096*2  = 90,177,536
  //   ub  @ 102.0 MB  : 4*11008*16*2  = 1,409,024
  //   vtT @ 103.3 MB  : 4*4096*16*2   = 524,288     (total ~103.8 MiB)
  char* wsp = (char*)d_ws;
  ushort_t* xb  = (ushort_t*)wsp;
  ushort_t* wb  = (ushort_t*)(wsp + (size_t)TOKENS * IN_F * 2);
  ushort_t* ubf = (ushort_t*)(wsp + (size_t)TOKENS * IN_F * 2 + (size_t)OUT_F * IN_F * 2);
  ushort_t* vtT = (ushort_t*)(wsp + (size_t)TOKENS * IN_F * 2 + (size_t)OUT_F * IN_F * 2 +
                              (size_t)N_U * 2);

  k_cvt_x<<<TOKENS * IN_F / 1024, 256, 0, stream>>>(x, xb);
  k_prep_uv<<<(N_U + N_VT) / 256, 256, 0, stream>>>(u, vt, ubf, vtT);
  k_build_w<<<(OUT_F / 128) * (IN_F / 128), 256, 0, stream>>>(qw, ubf, vtT, wb);
  k_gemm_bt<<<16 * (OUT_F / 256), 512, 0, stream>>>(xb, wb, out);
}

// Round 4
// 428.260 us; speedup vs baseline: 1.9489x; 1.0767x over previous
//
#include <hip/hip_runtime.h>
#include <cstdint>
#include <cstddef>

// Problem constants (from reference)
#define TOKENS 2048
#define IN_F   4096
#define OUT_F  11008
#define W_BIT  4
#define RANK   16
#define QWB    (OUT_F * IN_F / 8)   // 5,636,096 int32 "bytes" per bit-plane

typedef unsigned short ushort_t;
typedef __attribute__((ext_vector_type(8))) short   short8;   // 8 bf16 = 4 VGPRs (MFMA A/B frag)
typedef __attribute__((ext_vector_type(4))) float   floatx4;  // MFMA C/D frag

__device__ __forceinline__ ushort_t f2bf(float f) {
  union { float f; uint32_t u; } c; c.f = f;
  uint32_t r = c.u + 0x7FFFu + ((c.u >> 16) & 1u);  // RNE
  return (ushort_t)(r >> 16);
}

// async global->LDS, 16B per lane; lds pointer must be wave-uniform base (HW adds lane*16)
__device__ __forceinline__ void gl_lds16(const void* g, void* l) {
  __builtin_amdgcn_global_load_lds(
      (const __attribute__((address_space(1))) uint32_t*)g,
      (__attribute__((address_space(3))) uint32_t*)l, 16, 0, 0);
}

// ---------------- phase 0a: x fp32 -> bf16 ----------------
__global__ __launch_bounds__(256) void k_cvt_x(const float* __restrict__ x,
                                               ushort_t* __restrict__ xb) {
  int idx = blockIdx.x * 256 + threadIdx.x;
  float4 v = ((const float4*)x)[idx];
  ushort4 r;
  r.x = f2bf(v.x); r.y = f2bf(v.y); r.z = f2bf(v.z); r.w = f2bf(v.w);
  ((ushort4*)xb)[idx] = r;
}

// ---------------- phase 0b: u -> bf16 (same layout), vt -> bf16 transposed ----------------
#define N_U  (W_BIT * OUT_F * RANK)   // 704512
#define N_VT (W_BIT * RANK * IN_F)    // 262144
__global__ __launch_bounds__(256) void k_prep_uv(const float* __restrict__ u,
                                                 const float* __restrict__ vt,
                                                 ushort_t* __restrict__ ub,
                                                 ushort_t* __restrict__ vtT) {
  int idx = blockIdx.x * 256 + threadIdx.x;
  if (idx < N_U) {
    ub[idx] = f2bf(u[idx]);
  } else {
    int e = idx - N_U;                 // [0, N_VT)
    int b = e >> 16;                   // RANK*IN_F = 65536
    int r = e & 65535;
    int k = r >> 12;                   // IN_F = 4096
    int i = r & 4095;
    vtT[((size_t)b * IN_F + i) * RANK + k] = f2bf(vt[e]);
  }
}

// ---------------- phase 1: build w (bf16): MFMA product + LDS-staged sign apply ----
// REVERTED to the round-0 version verbatim: two blind "optimizations" (permuted b128
// sign reads; LDS-staged coalesced store) each correlated with a regression in the
// non-gemm time (206 -> 228 -> 250 us). This config measured best. No further edits
// until this kernel appears in the rocprof top-5 with real counters.
__global__ __launch_bounds__(256) void k_build_w(const int* __restrict__ qw,
                                                 const ushort_t* __restrict__ ub,
                                                 const ushort_t* __restrict__ vtT,
                                                 ushort_t* __restrict__ w) {
  __shared__ int qs[W_BIT * 128 * 20];  // 40 KB
  const int tid = threadIdx.x;
  const int ob = blockIdx.x / (IN_F / 128);
  const int ib = blockIdx.x % (IN_F / 128);
  const int o0 = ob * 128, i0 = ib * 128;
  const int lane = tid & 63, wv = tid >> 6;
  const int wm = (wv >> 1) * 64, wn = (wv & 1) * 64;
  const int l16 = lane & 15, q = lane >> 4;
  const bool qlo = (q < 2);
  const int koff = (q & 1) * 8;        // valid k-halves for q=0,1; q>=2 zeroed
  const short8 zf = (short8)0;

  // stage qw tile: 4 planes x 128 rows x 16 ints; 2048 int4 chunks, 8/thread, coalesced
  #pragma unroll
  for (int n = 0; n < 8; ++n) {
    int c = n * 256 + tid;             // [0, 2048)
    int b = c >> 9, rem = c & 511;
    int row = rem >> 2, part = rem & 3;
    int4 v = *(const int4*)(qw + (size_t)b * QWB +
                            (size_t)(o0 + row) * (IN_F / 8) + (i0 >> 3) + part * 4);
    *(int4*)&qs[(b * 128 + row) * 20 + part * 4] = v;
  }

  floatx4 acc[16];
  #pragma unroll
  for (int i = 0; i < 16; ++i) acc[i] = (floatx4){0.f, 0.f, 0.f, 0.f};

  const int qc_base = (wn >> 3) + (l16 >> 3);  // LDS int col for this lane (+ni*2)
  const int bit = l16 & 7;

  __syncthreads();

  #pragma unroll
  for (int b = 0; b < W_BIT; ++b) {
    short8 af[4], bfr[4];
    #pragma unroll
    for (int mi = 0; mi < 4; ++mi) {
      short8 v = *(const short8*)&ub[((size_t)b * OUT_F + o0 + wm + mi * 16 + l16) * RANK + koff];
      af[mi] = qlo ? v : zf;
    }
    #pragma unroll
    for (int ni = 0; ni < 4; ++ni) {
      short8 v = *(const short8*)&vtT[((size_t)b * IN_F + i0 + wn + ni * 16 + l16) * RANK + koff];
      bfr[ni] = qlo ? v : zf;
    }

    #pragma unroll
    for (int mi = 0; mi < 4; ++mi) {
      floatx4 p[4];
      #pragma unroll
      for (int ni = 0; ni < 4; ++ni)
        p[ni] = __builtin_amdgcn_mfma_f32_16x16x32_bf16(
            af[mi], bfr[ni], (floatx4){0.f, 0.f, 0.f, 0.f}, 0, 0, 0);
      // C layout: col = l16, row = q*4 + v4  [verified m89/m91]
      #pragma unroll
      for (int v4 = 0; v4 < 4; ++v4) {
        const int o_loc = wm + mi * 16 + q * 4 + v4;
        const int* qrow = &qs[(b * 128 + o_loc) * 20];
        #pragma unroll
        for (int ni = 0; ni < 4; ++ni) {
          int qv = qrow[qc_base + ni * 2];
          float pv = p[ni][v4];
          acc[mi * 4 + ni][v4] += ((qv >> bit) & 1) ? pv : -pv;
        }
      }
    }
  }

  // store: 16 consecutive lanes (l16) write 16 consecutive bf16 -> 32B segments
  #pragma unroll
  for (int mi = 0; mi < 4; ++mi) {
    #pragma unroll
    for (int v4 = 0; v4 < 4; ++v4) {
      const int o = o0 + wm + mi * 16 + q * 4 + v4;
      #pragma unroll
      for (int ni = 0; ni < 4; ++ni)
        w[(size_t)o * IN_F + i0 + wn + ni * 16 + l16] = f2bf(acc[mi * 4 + ni][v4]);
    }
  }
}

// ---------------- phase 2: y = x @ w^T  (bf16 MFMA, 6-slot ring + reg double-buffer) ----
// M=2048, N=11008, K=4096. BM=128, BN=256, K-step 32. 512 threads = 8 waves (2Mx4N),
// wave tile 64x64 = 4x4 frags of 16x16x32; 16 MFMA per wave per step.
//
// Round-3 ring (6 x 24KB LDS, 1 barrier/step, counted vmcnt) PLUS the round-1
// register frag double-buffer: phase u reads frags(u+1) into the ALTERNATE reg set
// while the 16 MFMAs consume the current set (loaded last phase) with ZERO LDS
// dependency. This removes the ~200+ cyc/phase ds_read issue+latency from the
// MFMA critical path (round-3: MfmaUtil 39.6% ~= elapsed ratio of pure MFMA issue).
//
// Per phase u (steady):
//   vmcnt(6)   // completes stage(u+1) (9 outstanding -> 6; NEVER drains mid-loop)
//   barrier    // publish slot(u+1) residency across waves
//   ds_read frags(u+1) -> alt set          (8 x b128)
//   issue STAGE(u+4) -> slot((u+4)%6) = slot((u-2)%6)
//   setprio(1); 16 MFMA on current set; setprio(0)
// Race proof: slot(u-2)'s last readers (phase u-3 ds_reads) completed before their
// MFMAs (reg dep, phase u-2), which precede barriers u-1,u; STAGE issues after
// barrier u. Tail peels u=124..127 with exact waits 6/3/0/none.
// Swizzle/addressing identical to rounds 1/3 (0 bank conflicts measured):
// chunk ^= ((row>>1)&3), inverse folded into per-lane GLOBAL source address.
// NO min-wave launch bound (round-2 lesson: 128-reg cap -> 800MB scratch spill).
#define NSTEP (IN_F / 32)   // 128
#define SLOT  24576         // A 8KB + B 16KB
#define NSLOT 6
__global__ __launch_bounds__(512) void k_gemm_bt(const ushort_t* __restrict__ A,  // [2048][4096]
                                                 const ushort_t* __restrict__ B,  // [11008][4096]
                                                 float* __restrict__ C) {         // [2048][11008]
  __shared__ __attribute__((aligned(16))) char lds[NSLOT * SLOT];  // 144 KB
  const int tid = threadIdx.x;
  const int wg = (blockIdx.x & 7) * 86 + (blockIdx.x >> 3);  // bijective XCD swizzle (688=8*86)
  const int bm = wg & 15;    // 16 M-tiles of 128
  const int bn = wg >> 4;    // 43 N-tiles of 256
  const int lane = tid & 63, wv = tid >> 6;
  const int wm = wv >> 2, wn = wv & 3;      // wave grid 2(M) x 4(N), wave tile 64x64
  const int l16 = lane & 15, q = lane >> 4;
  const int sQ = q ^ ((l16 >> 1) & 3);      // read-side swizzled 16B-chunk slot (thread const)

  const size_t ar = (size_t)bm * 128, br = (size_t)bn * 256;
  // staging: A-tile 128x32 = 512 chunks (1/thread); B-tile 256x32 = 1024 (2/thread)
  // chunk c: row = c>>2, dest 16B-slot = c&3, source k-chunk = slot ^ ((row>>1)&3)
  const int qsrc = (tid & 3) ^ ((tid >> 3) & 3);
  const ushort_t* Ae  = A + (ar + (tid >> 2)) * IN_F + qsrc * 8;
  const ushort_t* B0e = B + (br + (tid >> 2)) * IN_F + qsrc * 8;
  const ushort_t* B1e = B + (br + 128 + (tid >> 2)) * IN_F + qsrc * 8;
  const int ldsoff = (tid & 448) * 16;      // wave-uniform dest base (HW adds lane*16)
  const int aFrag = (wm * 64 + l16) * 64 + sQ * 16;   // byte off within A region (+mi*1024)
  const int bFrag = (wn * 64 + l16) * 64 + sQ * 16;   // byte off within B region (+ni*1024)

  floatx4 acc[4][4];
  #pragma unroll
  for (int mi = 0; mi < 4; ++mi)
    #pragma unroll
    for (int ni = 0; ni < 4; ++ni) acc[mi][ni] = (floatx4){0.f, 0.f, 0.f, 0.f};

  short8 fa0[4], fb0[4], fa1[4], fb1[4];
  int sLd = SLOT;            // byte offset of slot holding frags(u+1) at phase u
  int sWr = 4 * SLOT;        // byte offset of slot receiving STAGE(u+4) at phase u

#define STAGEK(kt, off) do {                                                 \
    const size_t _k0 = (size_t)(kt) * 32;                                    \
    char* _d = lds + (off) + ldsoff;                                         \
    gl_lds16(Ae + _k0,  _d);                                                 \
    gl_lds16(B0e + _k0, _d + 8192);                                          \
    gl_lds16(B1e + _k0, _d + 16384);                                         \
  } while (0)

#define LDFR(FA, FB, off) do {                                               \
    const char* _ab = lds + (off);                                           \
    const char* _bb = _ab + 8192;                                            \
    _Pragma("unroll") for (int mi = 0; mi < 4; ++mi)                         \
      FA[mi] = *(const short8*)(_ab + aFrag + mi * 1024);                    \
    _Pragma("unroll") for (int ni = 0; ni < 4; ++ni)                         \
      FB[ni] = *(const short8*)(_bb + bFrag + ni * 1024);                    \
  } while (0)

#define MFMA16(MA, MB) do {                                                  \
    __builtin_amdgcn_s_setprio(1);                                           \
    _Pragma("unroll") for (int mi = 0; mi < 4; ++mi)                         \
      _Pragma("unroll") for (int ni = 0; ni < 4; ++ni)                       \
        acc[mi][ni] = __builtin_amdgcn_mfma_f32_16x16x32_bf16(               \
            MA[mi], MB[ni], acc[mi][ni], 0, 0, 0);                           \
    __builtin_amdgcn_s_setprio(0);                                           \
  } while (0)

#define PHASE(u_, VM, DO_STAGE, FA, FB, MA, MB) do {                         \
    asm volatile(VM ::: "memory");                                           \
    __builtin_amdgcn_s_barrier();                                            \
    asm volatile("" ::: "memory");                                           \
    LDFR(FA, FB, sLd);                   /* frags of step u_+1, alt set */   \
    if (DO_STAGE) STAGEK((u_) + 4, sWr);                                     \
    MFMA16(MA, MB);                      /* step u_, zero LDS dependency */  \
    sLd += SLOT; if (sLd == NSLOT * SLOT) sLd = 0;                           \
    sWr += SLOT; if (sWr == NSLOT * SLOT) sWr = 0;                           \
  } while (0)

  // prologue: stage steps 0..3 into slots 0..3 (12 loads in flight), frags(0) -> set0
  #pragma unroll
  for (int p = 0; p < 4; ++p) STAGEK(p, p * SLOT);
  asm volatile("s_waitcnt vmcnt(9)" ::: "memory");
  __builtin_amdgcn_s_barrier();
  asm volatile("" ::: "memory");
  LDFR(fa0, fb0, 0);

  // steady: phases u=0..123 (even count), stage u+4, wait vmcnt(6)
  for (int u = 0; u < NSTEP - 4; u += 2) {
    PHASE(u,     "s_waitcnt vmcnt(6)", true, fa1, fb1, fa0, fb0);
    PHASE(u + 1, "s_waitcnt vmcnt(6)", true, fa0, fb0, fa1, fb1);
  }
  // tail: u=124..126 shrink waits 6/3/0; u=127 is MFMA-only
  PHASE(NSTEP - 4, "s_waitcnt vmcnt(6)", false, fa1, fb1, fa0, fb0);
  PHASE(NSTEP - 3, "s_waitcnt vmcnt(3)", false, fa0, fb0, fa1, fb1);
  PHASE(NSTEP - 2, "s_waitcnt vmcnt(0)", false, fa1, fb1, fa0, fb0);
  MFMA16(fa1, fb1);                      // step 127 (frags loaded in previous phase)

#undef STAGEK
#undef LDFR
#undef MFMA16
#undef PHASE

  // C/D layout: col = lane&15, row = (lane>>4)*4 + reg  [verified m89/m91]
  #pragma unroll
  for (int mi = 0; mi < 4; ++mi) {
    #pragma unroll
    for (int ni = 0; ni < 4; ++ni) {
      #pragma unroll
      for (int v = 0; v < 4; ++v) {
        int r = bm * 128 + wm * 64 + mi * 16 + q * 4 + v;
        int c = bn * 256 + wn * 64 + ni * 16 + l16;
        C[(size_t)r * OUT_F + c] = acc[mi][ni][v];
      }
    }
  }
}

extern "C" void kernel_launch(void* const* d_in, const int* in_sizes, int n_in,
                              void* d_out, int out_size, void* d_ws, size_t ws_size,
                              hipStream_t stream) {
  (void)in_sizes; (void)n_in; (void)out_size; (void)ws_size;
  const float* x  = (const float*)d_in[0];
  const int*   qw = (const int*)d_in[1];
  const float* u  = (const float*)d_in[2];
  const float* vt = (const float*)d_in[3];
  float* out = (float*)d_out;

  // workspace layout (bytes):
  //   xb  @ 0         : 2048*4096*2   = 16,777,216
  //   wb  @ 16.0 MB   : 11008*4096*2  = 90,177,536
  //   ub  @ 102.0 MB  : 4*11008*16*2  = 1,409,024
  //   vtT @ 103.3 MB  : 4*4096*16*2   = 524,288     (total ~103.8 MiB)
  char* wsp = (char*)d_ws;
  ushort_t* xb  = (ushort_t*)wsp;
  ushort_t* wb  = (ushort_t*)(wsp + (size_t)TOKENS * IN_F * 2);
  ushort_t* ubf = (ushort_t*)(wsp + (size_t)TOKENS * IN_F * 2 + (size_t)OUT_F * IN_F * 2);
  ushort_t* vtT = (ushort_t*)(wsp + (size_t)TOKENS * IN_F * 2 + (size_t)OUT_F * IN_F * 2 +
                              (size_t)N_U * 2);

  k_cvt_x<<<TOKENS * IN_F / 1024, 256, 0, stream>>>(x, xb);
  k_prep_uv<<<(N_U + N_VT) / 256, 256, 0, stream>>>(u, vt, ubf, vtT);
  k_build_w<<<(OUT_F / 128) * (IN_F / 128), 256, 0, stream>>>(qw, ubf, vtT, wb);
  k_gemm_bt<<<16 * (OUT_F / 256), 512, 0, stream>>>(xb, wb, out);
}